// Round 20
// baseline (172.161 us; speedup 1.0000x reference)
//
#include <hip/hip_runtime.h>

// GAT forward. Atomic-free multisplit sort + wave-per-node consumers.
//   fused:   node_transform (MFMA bf16: h=x@W1 fp32-accum -> h stored DENSE
//            bf16; a=h·Wp[:64], b=h·Wp[64:]) || pass1 LDS histogram of dst>>7
//            NT blocks stage W1 ONCE then process 4 x 64-node groups.
//   colscan: per-bin exclusive prefix over blocks in XCD-GROUPED order
//            (g = 8*(i%gp) + i/gp): same-XCD blocks' slots contiguous.
//   binscan: exclusive scan S -> binStart; offsets[N]=E
//   pass2:   re-read edges, num=exp(lrelu(a[dst]+b[src]+bp)); global-atomic
//            denom[dst] += num (100K L2-resident counters: cheap regime);
//            write {dl<<17|src, num} to exact slot binStart+C[g][bin]+ldsCur
//   localsort: per bin LDS counting sort to exact dst order; emits offsets;
//            scatter rewrites staging as {src, w} with w = num/(denom[src]
//            +1e-16)  (weight PRE-FOLDED so aggregate has no dependent
//            gather — round 17/19 showed that chain cost +4.5us)
//   aggregate: wave per node; preload = one 8B load; 4 edges per uint2
//            gather step (round-16 measured-best form).
// (alpha denominator gathered at SRC per the reference's quirk.)

#define MAXB 1024          // max dst bins (N/128); 782 for N=100000
#define EPB 4096           // edges per pass1/pass2 block
#define BIN_CAP 2560       // max edges per 128-node bin (mean 1600, sigma 40)

typedef __attribute__((ext_vector_type(8))) short short8v;
typedef __attribute__((ext_vector_type(4))) float floatx4;

static __device__ __forceinline__ float bf2f(unsigned short u) {
    unsigned v = (unsigned)u << 16;
    return __builtin_bit_cast(float, v);
}
static __device__ __forceinline__ unsigned short f2bf(float f) {
    unsigned u = __builtin_bit_cast(unsigned, f);
    u = (u + 0x7FFFu + ((u >> 16) & 1u)) >> 16;   // round-to-nearest-even
    return (unsigned short)u;
}

// ---------------- fused: pass1 histogram (blocks [0,G8)) + NT-MFMA ---------
__global__ __launch_bounds__(256) void fused_nt_count_kernel(
    const float* __restrict__ x, const float* __restrict__ W1,
    const float* __restrict__ Wp, const int* __restrict__ ei,
    unsigned short* __restrict__ hbD, float* __restrict__ aArr,
    float* __restrict__ bArr, int* __restrict__ C, int N, int E, int G8, int B)
{
    __shared__ __align__(16) unsigned short w1b[4][4][4][16][8]; // 16KB
    __shared__ int cnt[MAXB];                                    // 4 KB
    const int tid = threadIdx.x;

    if (blockIdx.x < G8) {
        const int g = blockIdx.x;
        for (int i = tid; i < B; i += 256) cnt[i] = 0;
        __syncthreads();
        const int base = g * EPB;
        #pragma unroll
        for (int k = 0; k < EPB / 256; ++k) {
            int e = base + k * 256 + tid;
            if (e < E) atomicAdd(&cnt[ei[E + e] >> 7], 1);
        }
        __syncthreads();
        for (int i = tid; i < B; i += 256) C[(size_t)g * B + i] = cnt[i];
        return;
    }

    // ---- stage W1 as bf16 ONCE, swizzled so each B-fragment is contiguous -
    for (int i = tid; i < 128 * 64; i += 256) {
        int k = i >> 6, o = i & 63;
        w1b[k >> 5][o >> 4][(k >> 3) & 3][o & 15][k & 7] = f2bf(W1[i]);
    }

    const int w = tid >> 6, lane = tid & 63;
    const int hi = lane >> 4, col = lane & 15;
    float wpa4[4], wpb4[4];
    #pragma unroll
    for (int ot = 0; ot < 4; ++ot) {
        wpa4[ot] = Wp[ot * 16 + col];
        wpb4[ot] = Wp[64 + ot * 16 + col];
    }
    __syncthreads();

    // ---- 4 x 64-node groups per block (no barriers between: LDS read-only)
    const int grp0 = (blockIdx.x - G8) * 4;
    #pragma unroll
    for (int gi = 0; gi < 4; ++gi) {
        const int gbase = (grp0 + gi) * 64;
        if (gbase >= N) break;
        const int n0 = gbase + w * 16;
        int arow = n0 + col; if (arow >= N) arow = N - 1;
        const float* xrow = x + (size_t)arow * 128 + hi * 8;

        floatx4 acc[4] = {{0.f,0.f,0.f,0.f},{0.f,0.f,0.f,0.f},
                          {0.f,0.f,0.f,0.f},{0.f,0.f,0.f,0.f}};
        #pragma unroll
        for (int kb = 0; kb < 4; ++kb) {
            float4 x0 = *reinterpret_cast<const float4*>(xrow + kb * 32);
            float4 x1 = *reinterpret_cast<const float4*>(xrow + kb * 32 + 4);
            short8v af;
            af[0] = (short)f2bf(x0.x); af[1] = (short)f2bf(x0.y);
            af[2] = (short)f2bf(x0.z); af[3] = (short)f2bf(x0.w);
            af[4] = (short)f2bf(x1.x); af[5] = (short)f2bf(x1.y);
            af[6] = (short)f2bf(x1.z); af[7] = (short)f2bf(x1.w);
            #pragma unroll
            for (int ot = 0; ot < 4; ++ot) {
                short8v bf = *reinterpret_cast<const short8v*>(&w1b[kb][ot][hi][col][0]);
                acc[ot] = __builtin_amdgcn_mfma_f32_16x16x32_bf16(af, bf, acc[ot], 0, 0, 0);
            }
        }

        // ---- epilogue: h store as DENSE bf16 ----
        #pragma unroll
        for (int ot = 0; ot < 4; ++ot) {
            #pragma unroll
            for (int r = 0; r < 4; ++r) {
                int n = n0 + hi * 4 + r;
                if (n < N) hbD[(size_t)n * 64 + ot * 16 + col] = f2bf(acc[ot][r]);
            }
        }
        // ---- a/b projections from fp32 accumulators ----
        #pragma unroll
        for (int r = 0; r < 4; ++r) {
            float pa = acc[0][r] * wpa4[0] + acc[1][r] * wpa4[1]
                     + acc[2][r] * wpa4[2] + acc[3][r] * wpa4[3];
            float pb = acc[0][r] * wpb4[0] + acc[1][r] * wpb4[1]
                     + acc[2][r] * wpb4[2] + acc[3][r] * wpb4[3];
            #pragma unroll
            for (int m = 1; m <= 8; m <<= 1) {
                pa += __shfl_xor(pa, m);
                pb += __shfl_xor(pb, m);
            }
            int n = n0 + hi * 4 + r;
            if (col == r && n < N) { aArr[n] = pa; bArr[n] = pb; }
        }
    }
}

// ---- colscan: per-bin exclusive prefix over blocks, XCD-GROUPED order -----
__global__ __launch_bounds__(256) void colscan_kernel(
    int* __restrict__ C, int* __restrict__ S, int G8, int B)
{
    __shared__ int s[256];
    const int b = blockIdx.x, t = threadIdx.x;
    const int gp = G8 >> 3;
    int i0 = 2 * t, i1 = 2 * t + 1;
    int ga = 8 * (i0 % gp) + (i0 / gp);
    int gb = 8 * (i1 % gp) + (i1 / gp);
    int c0 = (i0 < G8) ? C[(size_t)ga * B + b] : 0;
    int c1 = (i1 < G8) ? C[(size_t)gb * B + b] : 0;
    int v = c0 + c1;
    s[t] = v;
    __syncthreads();
    for (int off = 1; off < 256; off <<= 1) {
        int u = (t >= off) ? s[t - off] : 0;
        __syncthreads();
        s[t] += u;
        __syncthreads();
    }
    int ex = s[t] - v;
    if (i0 < G8) C[(size_t)ga * B + b] = ex;
    if (i1 < G8) C[(size_t)gb * B + b] = ex + c0;
    if (t == 255) S[b] = s[255];
}

// ---- binscan: exclusive scan of S[B] -> binStart[B+1]; offsets[N]=E --------
__global__ __launch_bounds__(256) void binscan_kernel(
    const int* __restrict__ S, int* __restrict__ binStart,
    int* __restrict__ offsets, int B, int N, int E)
{
    __shared__ int ts[256];
    const int t = threadIdx.x;
    const int chunk = (B + 255) >> 8;
    const int base = t * chunk, lim = min(B, base + chunk);
    int s = 0;
    for (int i = base; i < lim; ++i) s += S[i];
    ts[t] = s;
    __syncthreads();
    for (int off = 1; off < 256; off <<= 1) {
        int u = (t >= off) ? ts[t - off] : 0;
        __syncthreads();
        ts[t] += u;
        __syncthreads();
    }
    int run = ts[t] - s;
    for (int i = base; i < lim; ++i) { binStart[i] = run; run += S[i]; }
    if (t == 0) { binStart[B] = E; offsets[N] = E; }
}

// ---- pass2: multisplit scatter + global-atomic denom (100K counters) ------
__global__ __launch_bounds__(1024) void pass2_kernel(
    const int* __restrict__ ei, const float* __restrict__ aArr,
    const float* __restrict__ bArr, const float* __restrict__ bp,
    const int* __restrict__ C, const int* __restrict__ binStart,
    int2* __restrict__ staging, float* __restrict__ denom, int E, int B)
{
    __shared__ int cur[MAXB];
    const int g = blockIdx.x, t = threadIdx.x;
    for (int i = t; i < B; i += 1024)
        cur[i] = binStart[i] + C[(size_t)g * B + i];
    __syncthreads();
    const float bp0 = bp[0];
    const int base = g * EPB;
    #pragma unroll
    for (int k = 0; k < EPB / 1024; ++k) {
        int e = base + k * 1024 + t;
        if (e >= E) break;
        int src = ei[e];
        int dst = ei[E + e];
        float s = aArr[dst] + bArr[src] + bp0;
        s = (s >= 0.f) ? s : 0.2f * s;
        float num = __expf(s);
        atomicAdd(&denom[dst], num);         // 100K counters: cheap regime
        int bin = dst >> 7;
        int pos = atomicAdd(&cur[bin], 1);   // LDS atomic
        staging[pos] = make_int2(((dst & 127) << 17) | src, __float_as_int(num));
    }
}

// ---- localsort: per bin, exact dst order + CSR offsets + weight pre-fold ---
__global__ __launch_bounds__(256) void localsort_kernel(
    const int* __restrict__ binStart, int2* __restrict__ staging,
    int* __restrict__ offsets, const float* __restrict__ denom, int N)
{
    __shared__ int2 sEnt[BIN_CAP];       // 20 KB
    __shared__ int sCnt[256], sScan[256], sCur[128];
    const int b = blockIdx.x, t = threadIdx.x;
    const int sBeg = binStart[b];
    const int count = min(binStart[b + 1] - sBeg, BIN_CAP);

    sCnt[t] = 0;
    if (t < 128) sCur[t] = 0;
    __syncthreads();
    for (int i = t; i < count; i += 256) {
        int2 e = staging[sBeg + i];
        sEnt[i] = e;
        atomicAdd(&sCnt[e.x >> 17], 1);
    }
    __syncthreads();
    int v = sCnt[t];
    sScan[t] = v;
    __syncthreads();
    for (int off = 1; off < 256; off <<= 1) {
        int u = (t >= off) ? sScan[t - off] : 0;
        __syncthreads();
        sScan[t] += u;
        __syncthreads();
    }
    int ex = sScan[t] - v;
    __syncthreads();
    sScan[t] = ex;                       // exclusive scan in place
    const int n0 = b << 7;
    const int Cl = min(128, N - n0);
    if (t < Cl) offsets[n0 + t] = sBeg + ex;
    __syncthreads();
    for (int i = t; i < count; i += 256) {
        int2 e = sEnt[i];
        int dl = e.x >> 17;
        int src = e.x & 0x1FFFF;
        float wgt = __int_as_float(e.y) / (denom[src] + 1e-16f);  // SRC quirk
        int pos = sBeg + sScan[dl] + atomicAdd(&sCur[dl], 1);
        staging[pos] = make_int2(src, __float_as_int(wgt));   // {src, w}
    }
}

// ---------------- aggregate: wave per dst node, 4 edges per uint2 gather ----
// h row = 64 bf16 = 128B = 16 uint2 (256B-aligned array). Weight is already
// pre-folded into staging (.y = w): preload is ONE 8B load, no dependent
// gather (round 17/19 lesson). quarter = lane>>4 picks edge j..j+3;
// cg = lane&15 picks a bf16x4 channel group.
__global__ __launch_bounds__(256) void aggregate_kernel(
    const int* __restrict__ offsets, const int2* __restrict__ sortedPair,
    const uint2* __restrict__ hbQ, const float* __restrict__ bias,
    float* __restrict__ out, int N)
{
    int gw = (blockIdx.x * blockDim.x + threadIdx.x) >> 6;
    int lane = threadIdx.x & 63;
    if (gw >= N) return;
    int beg = offsets[gw], end = offsets[gw + 1];
    const int quarter = lane >> 4;
    const int cg = lane & 15;
    float a0 = 0.f, a1 = 0.f, a2 = 0.f, a3 = 0.f;
    for (int e0 = beg; e0 < end; e0 += 64) {
        int idx = e0 + lane;
        int srcL = 0; float wL = 0.f;
        if (idx < end) {
            int2 p = sortedPair[idx];
            srcL = p.x;
            wL = __int_as_float(p.y);
        }
        int cnt = min(64, end - e0);
        int j = 0;
        for (; j + 16 <= cnt; j += 16) {
            #pragma unroll
            for (int u = 0; u < 4; ++u) {
                int jj = j + 4 * u + quarter;
                int s = __shfl(srcL, jj);
                float wv = __shfl(wL, jj);
                uint2 g = hbQ[(size_t)s * 16 + cg];
                a0 = fmaf(bf2f((unsigned short)(g.x & 0xFFFFu)), wv, a0);
                a1 = fmaf(bf2f((unsigned short)(g.x >> 16)), wv, a1);
                a2 = fmaf(bf2f((unsigned short)(g.y & 0xFFFFu)), wv, a2);
                a3 = fmaf(bf2f((unsigned short)(g.y >> 16)), wv, a3);
            }
        }
        for (; j < cnt; j += 4) {
            int jj = j + quarter;           // <= 63 always (j<=60, quarter<=3)
            int s = __shfl(srcL, jj);
            float wv = __shfl(wL, jj);
            uint2 g = hbQ[(size_t)s * 16 + cg];
            a0 = fmaf(bf2f((unsigned short)(g.x & 0xFFFFu)), wv, a0);
            a1 = fmaf(bf2f((unsigned short)(g.x >> 16)), wv, a1);
            a2 = fmaf(bf2f((unsigned short)(g.y & 0xFFFFu)), wv, a2);
            a3 = fmaf(bf2f((unsigned short)(g.y >> 16)), wv, a3);
        }
    }
    a0 += __shfl_xor(a0, 16); a0 += __shfl_xor(a0, 32);
    a1 += __shfl_xor(a1, 16); a1 += __shfl_xor(a1, 32);
    a2 += __shfl_xor(a2, 16); a2 += __shfl_xor(a2, 32);
    a3 += __shfl_xor(a3, 16); a3 += __shfl_xor(a3, 32);
    if (lane < 16) {
        float4 bq = reinterpret_cast<const float4*>(bias)[cg];
        float4 o;
        o.x = a0 + bq.x; o.y = a1 + bq.y; o.z = a2 + bq.z; o.w = a3 + bq.w;
        reinterpret_cast<float4*>(out)[(size_t)gw * 16 + cg] = o;
    }
}

extern "C" void kernel_launch(void* const* d_in, const int* in_sizes, int n_in,
                              void* d_out, int out_size, void* d_ws, size_t ws_size,
                              hipStream_t stream) {
    const float* x    = (const float*)d_in[0];
    const int*   ei   = (const int*)d_in[1];
    // d_in[2] = rank_mapping (unused)
    const float* W1   = (const float*)d_in[3];
    const float* Wp   = (const float*)d_in[4];
    const float* bp   = (const float*)d_in[5];
    const float* bias = (const float*)d_in[6];
    float* out = (float*)d_out;

    const int N = in_sizes[0] / 128;
    const int E = in_sizes[1] / 2;
    const int B = (N + 127) >> 7;            // dst bins of 128 nodes (782)
    const int G = (E + EPB - 1) / EPB;       // real pass blocks (306)
    const int G8 = (G + 7) & ~7;             // padded to XCD multiple (312)
    const int NTB = (N + 255) / 256;         // NT blocks, 256 nodes each (391)

    // workspace layout:
    // hbD[N*64 bf16, at base: 256B-aligned] | a[N] | b[N] | denom[N] |
    // C[G8*B] | S[B] | binStart[B+1] | offsets[N+1] | staging[E] int2
    unsigned short* hbD = (unsigned short*)d_ws;       // base is page-aligned
    float* aArr     = (float*)(hbD + (size_t)N * 64);
    float* bArr     = aArr + N;
    float* denom    = bArr + N;
    int*   C        = (int*)(denom + N);
    int*   S        = C + (size_t)G8 * B;
    int*   binStart = S + B;
    int*   offsets  = binStart + (B + 1);
    int*   stRaw    = offsets + (N + 1);
    stRaw = (int*)(((uintptr_t)stRaw + 7) & ~(uintptr_t)7);
    int2*  staging  = (int2*)stRaw;

    hipMemsetAsync(denom, 0, (size_t)N * sizeof(float), stream);

    // pass1 blocks FIRST so they dispatch early and overlap node transform.
    fused_nt_count_kernel<<<G8 + NTB, 256, 0, stream>>>(
        x, W1, Wp, ei, hbD, aArr, bArr, C, N, E, G8, B);

    colscan_kernel<<<B, 256, 0, stream>>>(C, S, G8, B);

    binscan_kernel<<<1, 256, 0, stream>>>(S, binStart, offsets, B, N, E);

    pass2_kernel<<<G8, 1024, 0, stream>>>(ei, aArr, bArr, bp, C, binStart,
                                          staging, denom, E, B);

    localsort_kernel<<<B, 256, 0, stream>>>(binStart, staging, offsets, denom, N);

    aggregate_kernel<<<(N * 64 + 255) / 256, 256, 0, stream>>>(
        offsets, staging, reinterpret_cast<const uint2*>(hbD), bias, out, N);
}

// Round 21
// 121.996 us; speedup vs baseline: 1.4112x; 1.4112x over previous
//
#include <hip/hip_runtime.h>

// GAT forward. Atomic-free multisplit sort + wave-per-node consumers.
//   fused:   node_transform (MFMA bf16: h=x@W1 fp32-accum -> h stored DENSE
//            bf16; a=h·Wp[:64], b=h·Wp[64:]) || pass1 LDS histogram of dst>>7
//            NT blocks stage W1 ONCE then process 4 x 64-node groups.
//   colscan: per-bin exclusive prefix over blocks in XCD-GROUPED order.
//   binscan: exclusive scan S -> binStart; offsets[N]=E
//   pass2:   re-read edges, num=exp(lrelu(a[dst]+b[src]+bp)); write
//            {dl<<17|src, num} to exact slot binStart+C[g][bin]+ldsCur
//            (NO global atomics — round 20's denom atomic cost 40MB of
//             cross-XCD line bounce and doubled pass2)
//   denom:   per bin: LDS dsum[128] from staging, ONE coalesced denom write
//   localsort: per bin LDS counting sort to exact dst order; emits offsets;
//            scatter rewrites staging as {src, w}, w = num/(denom[src]+1e-16)
//            (weight PRE-FOLDED so aggregate has no dependent gather)
//   aggregate: wave per node; preload = one 8B load; 4 edges per uint2
//            gather step (round-16 measured-best form).
// (alpha denominator gathered at SRC per the reference's quirk.)

#define MAXB 1024          // max dst bins (N/128); 782 for N=100000
#define EPB 4096           // edges per pass1/pass2 block
#define BIN_CAP 2560       // max edges per 128-node bin (mean 1600, sigma 40)

typedef __attribute__((ext_vector_type(8))) short short8v;
typedef __attribute__((ext_vector_type(4))) float floatx4;

static __device__ __forceinline__ float bf2f(unsigned short u) {
    unsigned v = (unsigned)u << 16;
    return __builtin_bit_cast(float, v);
}
static __device__ __forceinline__ unsigned short f2bf(float f) {
    unsigned u = __builtin_bit_cast(unsigned, f);
    u = (u + 0x7FFFu + ((u >> 16) & 1u)) >> 16;   // round-to-nearest-even
    return (unsigned short)u;
}

// ---------------- fused: pass1 histogram (blocks [0,G8)) + NT-MFMA ---------
__global__ __launch_bounds__(256) void fused_nt_count_kernel(
    const float* __restrict__ x, const float* __restrict__ W1,
    const float* __restrict__ Wp, const int* __restrict__ ei,
    unsigned short* __restrict__ hbD, float* __restrict__ aArr,
    float* __restrict__ bArr, int* __restrict__ C, int N, int E, int G8, int B)
{
    __shared__ __align__(16) unsigned short w1b[4][4][4][16][8]; // 16KB
    __shared__ int cnt[MAXB];                                    // 4 KB
    const int tid = threadIdx.x;

    if (blockIdx.x < G8) {
        const int g = blockIdx.x;
        for (int i = tid; i < B; i += 256) cnt[i] = 0;
        __syncthreads();
        const int base = g * EPB;
        #pragma unroll
        for (int k = 0; k < EPB / 256; ++k) {
            int e = base + k * 256 + tid;
            if (e < E) atomicAdd(&cnt[ei[E + e] >> 7], 1);
        }
        __syncthreads();
        for (int i = tid; i < B; i += 256) C[(size_t)g * B + i] = cnt[i];
        return;
    }

    // ---- stage W1 as bf16 ONCE, swizzled so each B-fragment is contiguous -
    for (int i = tid; i < 128 * 64; i += 256) {
        int k = i >> 6, o = i & 63;
        w1b[k >> 5][o >> 4][(k >> 3) & 3][o & 15][k & 7] = f2bf(W1[i]);
    }

    const int w = tid >> 6, lane = tid & 63;
    const int hi = lane >> 4, col = lane & 15;
    float wpa4[4], wpb4[4];
    #pragma unroll
    for (int ot = 0; ot < 4; ++ot) {
        wpa4[ot] = Wp[ot * 16 + col];
        wpb4[ot] = Wp[64 + ot * 16 + col];
    }
    __syncthreads();

    // ---- 4 x 64-node groups per block (no barriers between: LDS read-only)
    const int grp0 = (blockIdx.x - G8) * 4;
    #pragma unroll
    for (int gi = 0; gi < 4; ++gi) {
        const int gbase = (grp0 + gi) * 64;
        if (gbase >= N) break;
        const int n0 = gbase + w * 16;
        int arow = n0 + col; if (arow >= N) arow = N - 1;
        const float* xrow = x + (size_t)arow * 128 + hi * 8;

        floatx4 acc[4] = {{0.f,0.f,0.f,0.f},{0.f,0.f,0.f,0.f},
                          {0.f,0.f,0.f,0.f},{0.f,0.f,0.f,0.f}};
        #pragma unroll
        for (int kb = 0; kb < 4; ++kb) {
            float4 x0 = *reinterpret_cast<const float4*>(xrow + kb * 32);
            float4 x1 = *reinterpret_cast<const float4*>(xrow + kb * 32 + 4);
            short8v af;
            af[0] = (short)f2bf(x0.x); af[1] = (short)f2bf(x0.y);
            af[2] = (short)f2bf(x0.z); af[3] = (short)f2bf(x0.w);
            af[4] = (short)f2bf(x1.x); af[5] = (short)f2bf(x1.y);
            af[6] = (short)f2bf(x1.z); af[7] = (short)f2bf(x1.w);
            #pragma unroll
            for (int ot = 0; ot < 4; ++ot) {
                short8v bf = *reinterpret_cast<const short8v*>(&w1b[kb][ot][hi][col][0]);
                acc[ot] = __builtin_amdgcn_mfma_f32_16x16x32_bf16(af, bf, acc[ot], 0, 0, 0);
            }
        }

        // ---- epilogue: h store as DENSE bf16 ----
        #pragma unroll
        for (int ot = 0; ot < 4; ++ot) {
            #pragma unroll
            for (int r = 0; r < 4; ++r) {
                int n = n0 + hi * 4 + r;
                if (n < N) hbD[(size_t)n * 64 + ot * 16 + col] = f2bf(acc[ot][r]);
            }
        }
        // ---- a/b projections from fp32 accumulators ----
        #pragma unroll
        for (int r = 0; r < 4; ++r) {
            float pa = acc[0][r] * wpa4[0] + acc[1][r] * wpa4[1]
                     + acc[2][r] * wpa4[2] + acc[3][r] * wpa4[3];
            float pb = acc[0][r] * wpb4[0] + acc[1][r] * wpb4[1]
                     + acc[2][r] * wpb4[2] + acc[3][r] * wpb4[3];
            #pragma unroll
            for (int m = 1; m <= 8; m <<= 1) {
                pa += __shfl_xor(pa, m);
                pb += __shfl_xor(pb, m);
            }
            int n = n0 + hi * 4 + r;
            if (col == r && n < N) { aArr[n] = pa; bArr[n] = pb; }
        }
    }
}

// ---- colscan: per-bin exclusive prefix over blocks, XCD-GROUPED order -----
__global__ __launch_bounds__(256) void colscan_kernel(
    int* __restrict__ C, int* __restrict__ S, int G8, int B)
{
    __shared__ int s[256];
    const int b = blockIdx.x, t = threadIdx.x;
    const int gp = G8 >> 3;
    int i0 = 2 * t, i1 = 2 * t + 1;
    int ga = 8 * (i0 % gp) + (i0 / gp);
    int gb = 8 * (i1 % gp) + (i1 / gp);
    int c0 = (i0 < G8) ? C[(size_t)ga * B + b] : 0;
    int c1 = (i1 < G8) ? C[(size_t)gb * B + b] : 0;
    int v = c0 + c1;
    s[t] = v;
    __syncthreads();
    for (int off = 1; off < 256; off <<= 1) {
        int u = (t >= off) ? s[t - off] : 0;
        __syncthreads();
        s[t] += u;
        __syncthreads();
    }
    int ex = s[t] - v;
    if (i0 < G8) C[(size_t)ga * B + b] = ex;
    if (i1 < G8) C[(size_t)gb * B + b] = ex + c0;
    if (t == 255) S[b] = s[255];
}

// ---- binscan: exclusive scan of S[B] -> binStart[B+1]; offsets[N]=E --------
__global__ __launch_bounds__(256) void binscan_kernel(
    const int* __restrict__ S, int* __restrict__ binStart,
    int* __restrict__ offsets, int B, int N, int E)
{
    __shared__ int ts[256];
    const int t = threadIdx.x;
    const int chunk = (B + 255) >> 8;
    const int base = t * chunk, lim = min(B, base + chunk);
    int s = 0;
    for (int i = base; i < lim; ++i) s += S[i];
    ts[t] = s;
    __syncthreads();
    for (int off = 1; off < 256; off <<= 1) {
        int u = (t >= off) ? ts[t - off] : 0;
        __syncthreads();
        ts[t] += u;
        __syncthreads();
    }
    int run = ts[t] - s;
    for (int i = base; i < lim; ++i) { binStart[i] = run; run += S[i]; }
    if (t == 0) { binStart[B] = E; offsets[N] = E; }
}

// ---- pass2: deterministic multisplit scatter (no global atomics) -----------
__global__ __launch_bounds__(1024) void pass2_kernel(
    const int* __restrict__ ei, const float* __restrict__ aArr,
    const float* __restrict__ bArr, const float* __restrict__ bp,
    const int* __restrict__ C, const int* __restrict__ binStart,
    int2* __restrict__ staging, int E, int B)
{
    __shared__ int cur[MAXB];
    const int g = blockIdx.x, t = threadIdx.x;
    for (int i = t; i < B; i += 1024)
        cur[i] = binStart[i] + C[(size_t)g * B + i];
    __syncthreads();
    const float bp0 = bp[0];
    const int base = g * EPB;
    #pragma unroll
    for (int k = 0; k < EPB / 1024; ++k) {
        int e = base + k * 1024 + t;
        if (e >= E) break;
        int src = ei[e];
        int dst = ei[E + e];
        float s = aArr[dst] + bArr[src] + bp0;
        s = (s >= 0.f) ? s : 0.2f * s;
        float num = __expf(s);
        int bin = dst >> 7;
        int pos = atomicAdd(&cur[bin], 1);   // LDS atomic
        staging[pos] = make_int2(((dst & 127) << 17) | src, __float_as_int(num));
    }
}

// ---- denom: per bin LDS dsum from staging; ONE coalesced denom write -------
__global__ __launch_bounds__(256) void denom_kernel(
    const int* __restrict__ binStart, const int2* __restrict__ staging,
    float* __restrict__ denom, int N)
{
    __shared__ float dsum[128];
    const int b = blockIdx.x, t = threadIdx.x;
    if (t < 128) dsum[t] = 0.f;
    __syncthreads();
    const int beg = binStart[b], end = binStart[b + 1];
    for (int i = beg + t; i < end; i += 256) {
        int2 e = staging[i];
        atomicAdd(&dsum[e.x >> 17], __int_as_float(e.y));
    }
    __syncthreads();
    const int n0 = b << 7;
    const int Cl = min(128, N - n0);
    if (t < Cl) denom[n0 + t] = dsum[t];
}

// ---- localsort: per bin, exact dst order + CSR offsets + weight pre-fold ---
__global__ __launch_bounds__(256) void localsort_kernel(
    const int* __restrict__ binStart, int2* __restrict__ staging,
    int* __restrict__ offsets, const float* __restrict__ denom, int N)
{
    __shared__ int2 sEnt[BIN_CAP];       // 20 KB
    __shared__ int sCnt[256], sScan[256], sCur[128];
    const int b = blockIdx.x, t = threadIdx.x;
    const int sBeg = binStart[b];
    const int count = min(binStart[b + 1] - sBeg, BIN_CAP);

    sCnt[t] = 0;
    if (t < 128) sCur[t] = 0;
    __syncthreads();
    for (int i = t; i < count; i += 256) {
        int2 e = staging[sBeg + i];
        sEnt[i] = e;
        atomicAdd(&sCnt[e.x >> 17], 1);
    }
    __syncthreads();
    int v = sCnt[t];
    sScan[t] = v;
    __syncthreads();
    for (int off = 1; off < 256; off <<= 1) {
        int u = (t >= off) ? sScan[t - off] : 0;
        __syncthreads();
        sScan[t] += u;
        __syncthreads();
    }
    int ex = sScan[t] - v;
    __syncthreads();
    sScan[t] = ex;                       // exclusive scan in place
    const int n0 = b << 7;
    const int Cl = min(128, N - n0);
    if (t < Cl) offsets[n0 + t] = sBeg + ex;
    __syncthreads();
    for (int i = t; i < count; i += 256) {
        int2 e = sEnt[i];
        int dl = e.x >> 17;
        int src = e.x & 0x1FFFF;
        float wgt = __int_as_float(e.y) / (denom[src] + 1e-16f);  // SRC quirk
        int pos = sBeg + sScan[dl] + atomicAdd(&sCur[dl], 1);
        staging[pos] = make_int2(src, __float_as_int(wgt));   // {src, w}
    }
}

// ---------------- aggregate: wave per dst node, 4 edges per uint2 gather ----
// h row = 64 bf16 = 128B = 16 uint2 (256B-aligned array). Weight is already
// pre-folded into staging (.y = w): preload is ONE 8B load, no dependent
// gather (round 17/19 lesson). quarter = lane>>4 picks edge j..j+3;
// cg = lane&15 picks a bf16x4 channel group.
__global__ __launch_bounds__(256) void aggregate_kernel(
    const int* __restrict__ offsets, const int2* __restrict__ sortedPair,
    const uint2* __restrict__ hbQ, const float* __restrict__ bias,
    float* __restrict__ out, int N)
{
    int gw = (blockIdx.x * blockDim.x + threadIdx.x) >> 6;
    int lane = threadIdx.x & 63;
    if (gw >= N) return;
    int beg = offsets[gw], end = offsets[gw + 1];
    const int quarter = lane >> 4;
    const int cg = lane & 15;
    float a0 = 0.f, a1 = 0.f, a2 = 0.f, a3 = 0.f;
    for (int e0 = beg; e0 < end; e0 += 64) {
        int idx = e0 + lane;
        int srcL = 0; float wL = 0.f;
        if (idx < end) {
            int2 p = sortedPair[idx];
            srcL = p.x;
            wL = __int_as_float(p.y);
        }
        int cnt = min(64, end - e0);
        int j = 0;
        for (; j + 16 <= cnt; j += 16) {
            #pragma unroll
            for (int u = 0; u < 4; ++u) {
                int jj = j + 4 * u + quarter;
                int s = __shfl(srcL, jj);
                float wv = __shfl(wL, jj);
                uint2 g = hbQ[(size_t)s * 16 + cg];
                a0 = fmaf(bf2f((unsigned short)(g.x & 0xFFFFu)), wv, a0);
                a1 = fmaf(bf2f((unsigned short)(g.x >> 16)), wv, a1);
                a2 = fmaf(bf2f((unsigned short)(g.y & 0xFFFFu)), wv, a2);
                a3 = fmaf(bf2f((unsigned short)(g.y >> 16)), wv, a3);
            }
        }
        for (; j < cnt; j += 4) {
            int jj = j + quarter;           // <= 63 always (j<=60, quarter<=3)
            int s = __shfl(srcL, jj);
            float wv = __shfl(wL, jj);
            uint2 g = hbQ[(size_t)s * 16 + cg];
            a0 = fmaf(bf2f((unsigned short)(g.x & 0xFFFFu)), wv, a0);
            a1 = fmaf(bf2f((unsigned short)(g.x >> 16)), wv, a1);
            a2 = fmaf(bf2f((unsigned short)(g.y & 0xFFFFu)), wv, a2);
            a3 = fmaf(bf2f((unsigned short)(g.y >> 16)), wv, a3);
        }
    }
    a0 += __shfl_xor(a0, 16); a0 += __shfl_xor(a0, 32);
    a1 += __shfl_xor(a1, 16); a1 += __shfl_xor(a1, 32);
    a2 += __shfl_xor(a2, 16); a2 += __shfl_xor(a2, 32);
    a3 += __shfl_xor(a3, 16); a3 += __shfl_xor(a3, 32);
    if (lane < 16) {
        float4 bq = reinterpret_cast<const float4*>(bias)[cg];
        float4 o;
        o.x = a0 + bq.x; o.y = a1 + bq.y; o.z = a2 + bq.z; o.w = a3 + bq.w;
        reinterpret_cast<float4*>(out)[(size_t)gw * 16 + cg] = o;
    }
}

extern "C" void kernel_launch(void* const* d_in, const int* in_sizes, int n_in,
                              void* d_out, int out_size, void* d_ws, size_t ws_size,
                              hipStream_t stream) {
    const float* x    = (const float*)d_in[0];
    const int*   ei   = (const int*)d_in[1];
    // d_in[2] = rank_mapping (unused)
    const float* W1   = (const float*)d_in[3];
    const float* Wp   = (const float*)d_in[4];
    const float* bp   = (const float*)d_in[5];
    const float* bias = (const float*)d_in[6];
    float* out = (float*)d_out;

    const int N = in_sizes[0] / 128;
    const int E = in_sizes[1] / 2;
    const int B = (N + 127) >> 7;            // dst bins of 128 nodes (782)
    const int G = (E + EPB - 1) / EPB;       // real pass blocks (306)
    const int G8 = (G + 7) & ~7;             // padded to XCD multiple (312)
    const int NTB = (N + 255) / 256;         // NT blocks, 256 nodes each (391)

    // workspace layout:
    // hbD[N*64 bf16, at base: 256B-aligned] | a[N] | b[N] | denom[N] |
    // C[G8*B] | S[B] | binStart[B+1] | offsets[N+1] | staging[E] int2
    unsigned short* hbD = (unsigned short*)d_ws;       // base is page-aligned
    float* aArr     = (float*)(hbD + (size_t)N * 64);
    float* bArr     = aArr + N;
    float* denom    = bArr + N;
    int*   C        = (int*)(denom + N);
    int*   S        = C + (size_t)G8 * B;
    int*   binStart = S + B;
    int*   offsets  = binStart + (B + 1);
    int*   stRaw    = offsets + (N + 1);
    stRaw = (int*)(((uintptr_t)stRaw + 7) & ~(uintptr_t)7);
    int2*  staging  = (int2*)stRaw;

    // pass1 blocks FIRST so they dispatch early and overlap node transform.
    fused_nt_count_kernel<<<G8 + NTB, 256, 0, stream>>>(
        x, W1, Wp, ei, hbD, aArr, bArr, C, N, E, G8, B);

    colscan_kernel<<<B, 256, 0, stream>>>(C, S, G8, B);

    binscan_kernel<<<1, 256, 0, stream>>>(S, binStart, offsets, B, N, E);

    pass2_kernel<<<G8, 1024, 0, stream>>>(ei, aArr, bArr, bp, C, binStart,
                                          staging, E, B);

    denom_kernel<<<B, 256, 0, stream>>>(binStart, staging, denom, N);

    localsort_kernel<<<B, 256, 0, stream>>>(binStart, staging, offsets, denom, N);

    aggregate_kernel<<<(N * 64 + 255) / 256, 256, 0, stream>>>(
        offsets, staging, reinterpret_cast<const uint2*>(hbD), bias, out, N);
}

// Round 22
// 117.116 us; speedup vs baseline: 1.4700x; 1.0417x over previous
//
#include <hip/hip_runtime.h>

// GAT forward. Atomic-free multisplit sort + wave-per-node consumers.
// R22 = R18 skeleton (best measured: 118.7) + 256-node bins.
//   fused:   node_transform (MFMA bf16: h=x@W1 fp32-accum -> h stored DENSE
//            bf16; a=h·Wp[:64], b=h·Wp[64:]) || pass1 LDS histogram of dst>>8
//            NT blocks stage W1 ONCE then process 4 x 64-node groups.
//   colscan: per-bin exclusive prefix over blocks in XCD-GROUPED order.
//   binscan: exclusive scan S -> binStart; offsets[N]=E
//   pass2:   re-read edges, num=exp(lrelu(a[dst]+b[src]+bp)); write
//            {dl<<17|src, num} to exact slot binStart+C[g][bin]+ldsCur
//            (256-bins: 10.5 edges/bin/block -> ~84B store runs)
//   localsort: per bin (256 dsts, <=4096 edges in 32KB LDS) counting sort to
//            exact dst order; emits offsets and invD[n]=1/(dsum+1e-16)
//   aggregate: wave per node; preload folds w = num*invD[src]; 4 edges per
//            uint2 gather step (R16/R18 measured-best form).
// (alpha denominator gathered at SRC per the reference's quirk.)

#define MAXB 512           // max dst bins (N/256); 391 for N=100000
#define EPB 4096           // edges per pass1/pass2 block
#define BIN_CAP 4096       // max edges per 256-node bin (mean 3200, sigma 57)

typedef __attribute__((ext_vector_type(8))) short short8v;
typedef __attribute__((ext_vector_type(4))) float floatx4;

static __device__ __forceinline__ float bf2f(unsigned short u) {
    unsigned v = (unsigned)u << 16;
    return __builtin_bit_cast(float, v);
}
static __device__ __forceinline__ unsigned short f2bf(float f) {
    unsigned u = __builtin_bit_cast(unsigned, f);
    u = (u + 0x7FFFu + ((u >> 16) & 1u)) >> 16;   // round-to-nearest-even
    return (unsigned short)u;
}

// ---------------- fused: pass1 histogram (blocks [0,G8)) + NT-MFMA ---------
__global__ __launch_bounds__(256) void fused_nt_count_kernel(
    const float* __restrict__ x, const float* __restrict__ W1,
    const float* __restrict__ Wp, const int* __restrict__ ei,
    unsigned short* __restrict__ hbD, float* __restrict__ aArr,
    float* __restrict__ bArr, int* __restrict__ C, int N, int E, int G8, int B)
{
    __shared__ __align__(16) unsigned short w1b[4][4][4][16][8]; // 16KB
    __shared__ int cnt[MAXB];                                    // 2 KB
    const int tid = threadIdx.x;

    if (blockIdx.x < G8) {
        const int g = blockIdx.x;
        for (int i = tid; i < B; i += 256) cnt[i] = 0;
        __syncthreads();
        const int base = g * EPB;
        #pragma unroll
        for (int k = 0; k < EPB / 256; ++k) {
            int e = base + k * 256 + tid;
            if (e < E) atomicAdd(&cnt[ei[E + e] >> 8], 1);
        }
        __syncthreads();
        for (int i = tid; i < B; i += 256) C[(size_t)g * B + i] = cnt[i];
        return;
    }

    // ---- stage W1 as bf16 ONCE, swizzled so each B-fragment is contiguous -
    for (int i = tid; i < 128 * 64; i += 256) {
        int k = i >> 6, o = i & 63;
        w1b[k >> 5][o >> 4][(k >> 3) & 3][o & 15][k & 7] = f2bf(W1[i]);
    }

    const int w = tid >> 6, lane = tid & 63;
    const int hi = lane >> 4, col = lane & 15;
    float wpa4[4], wpb4[4];
    #pragma unroll
    for (int ot = 0; ot < 4; ++ot) {
        wpa4[ot] = Wp[ot * 16 + col];
        wpb4[ot] = Wp[64 + ot * 16 + col];
    }
    __syncthreads();

    // ---- 4 x 64-node groups per block (no barriers between: LDS read-only)
    const int grp0 = (blockIdx.x - G8) * 4;
    #pragma unroll
    for (int gi = 0; gi < 4; ++gi) {
        const int gbase = (grp0 + gi) * 64;
        if (gbase >= N) break;
        const int n0 = gbase + w * 16;
        int arow = n0 + col; if (arow >= N) arow = N - 1;
        const float* xrow = x + (size_t)arow * 128 + hi * 8;

        floatx4 acc[4] = {{0.f,0.f,0.f,0.f},{0.f,0.f,0.f,0.f},
                          {0.f,0.f,0.f,0.f},{0.f,0.f,0.f,0.f}};
        #pragma unroll
        for (int kb = 0; kb < 4; ++kb) {
            float4 x0 = *reinterpret_cast<const float4*>(xrow + kb * 32);
            float4 x1 = *reinterpret_cast<const float4*>(xrow + kb * 32 + 4);
            short8v af;
            af[0] = (short)f2bf(x0.x); af[1] = (short)f2bf(x0.y);
            af[2] = (short)f2bf(x0.z); af[3] = (short)f2bf(x0.w);
            af[4] = (short)f2bf(x1.x); af[5] = (short)f2bf(x1.y);
            af[6] = (short)f2bf(x1.z); af[7] = (short)f2bf(x1.w);
            #pragma unroll
            for (int ot = 0; ot < 4; ++ot) {
                short8v bf = *reinterpret_cast<const short8v*>(&w1b[kb][ot][hi][col][0]);
                acc[ot] = __builtin_amdgcn_mfma_f32_16x16x32_bf16(af, bf, acc[ot], 0, 0, 0);
            }
        }

        // ---- epilogue: h store as DENSE bf16 ----
        #pragma unroll
        for (int ot = 0; ot < 4; ++ot) {
            #pragma unroll
            for (int r = 0; r < 4; ++r) {
                int n = n0 + hi * 4 + r;
                if (n < N) hbD[(size_t)n * 64 + ot * 16 + col] = f2bf(acc[ot][r]);
            }
        }
        // ---- a/b projections from fp32 accumulators ----
        #pragma unroll
        for (int r = 0; r < 4; ++r) {
            float pa = acc[0][r] * wpa4[0] + acc[1][r] * wpa4[1]
                     + acc[2][r] * wpa4[2] + acc[3][r] * wpa4[3];
            float pb = acc[0][r] * wpb4[0] + acc[1][r] * wpb4[1]
                     + acc[2][r] * wpb4[2] + acc[3][r] * wpb4[3];
            #pragma unroll
            for (int m = 1; m <= 8; m <<= 1) {
                pa += __shfl_xor(pa, m);
                pb += __shfl_xor(pb, m);
            }
            int n = n0 + hi * 4 + r;
            if (col == r && n < N) { aArr[n] = pa; bArr[n] = pb; }
        }
    }
}

// ---- colscan: per-bin exclusive prefix over blocks, XCD-GROUPED order -----
__global__ __launch_bounds__(256) void colscan_kernel(
    int* __restrict__ C, int* __restrict__ S, int G8, int B)
{
    __shared__ int s[256];
    const int b = blockIdx.x, t = threadIdx.x;
    const int gp = G8 >> 3;
    int i0 = 2 * t, i1 = 2 * t + 1;
    int ga = 8 * (i0 % gp) + (i0 / gp);
    int gb = 8 * (i1 % gp) + (i1 / gp);
    int c0 = (i0 < G8) ? C[(size_t)ga * B + b] : 0;
    int c1 = (i1 < G8) ? C[(size_t)gb * B + b] : 0;
    int v = c0 + c1;
    s[t] = v;
    __syncthreads();
    for (int off = 1; off < 256; off <<= 1) {
        int u = (t >= off) ? s[t - off] : 0;
        __syncthreads();
        s[t] += u;
        __syncthreads();
    }
    int ex = s[t] - v;
    if (i0 < G8) C[(size_t)ga * B + b] = ex;
    if (i1 < G8) C[(size_t)gb * B + b] = ex + c0;
    if (t == 255) S[b] = s[255];
}

// ---- binscan: exclusive scan of S[B] -> binStart[B+1]; offsets[N]=E --------
__global__ __launch_bounds__(256) void binscan_kernel(
    const int* __restrict__ S, int* __restrict__ binStart,
    int* __restrict__ offsets, int B, int N, int E)
{
    __shared__ int ts[256];
    const int t = threadIdx.x;
    const int chunk = (B + 255) >> 8;
    const int base = t * chunk, lim = min(B, base + chunk);
    int s = 0;
    for (int i = base; i < lim; ++i) s += S[i];
    ts[t] = s;
    __syncthreads();
    for (int off = 1; off < 256; off <<= 1) {
        int u = (t >= off) ? ts[t - off] : 0;
        __syncthreads();
        ts[t] += u;
        __syncthreads();
    }
    int run = ts[t] - s;
    for (int i = base; i < lim; ++i) { binStart[i] = run; run += S[i]; }
    if (t == 0) { binStart[B] = E; offsets[N] = E; }
}

// ---- pass2: deterministic multisplit scatter (no global atomics) -----------
__global__ __launch_bounds__(1024) void pass2_kernel(
    const int* __restrict__ ei, const float* __restrict__ aArr,
    const float* __restrict__ bArr, const float* __restrict__ bp,
    const int* __restrict__ C, const int* __restrict__ binStart,
    int2* __restrict__ staging, int E, int B)
{
    __shared__ int cur[MAXB];
    const int g = blockIdx.x, t = threadIdx.x;
    for (int i = t; i < B; i += 1024)
        cur[i] = binStart[i] + C[(size_t)g * B + i];
    __syncthreads();
    const float bp0 = bp[0];
    const int base = g * EPB;
    #pragma unroll
    for (int k = 0; k < EPB / 1024; ++k) {
        int e = base + k * 1024 + t;
        if (e >= E) break;
        int src = ei[e];
        int dst = ei[E + e];
        float s = aArr[dst] + bArr[src] + bp0;
        s = (s >= 0.f) ? s : 0.2f * s;
        float num = __expf(s);
        int bin = dst >> 8;
        int pos = atomicAdd(&cur[bin], 1);   // LDS atomic
        staging[pos] = make_int2(((dst & 255) << 17) | src, __float_as_int(num));
    }
}

// ---- localsort: per 256-node bin, exact dst order + CSR offsets + invD -----
__global__ __launch_bounds__(256) void localsort_kernel(
    const int* __restrict__ binStart, int2* __restrict__ staging,
    int* __restrict__ offsets, float* __restrict__ invD, int N)
{
    __shared__ int2 sEnt[BIN_CAP];       // 32 KB
    __shared__ int sCnt[256], sScan[256], sCur[256];
    __shared__ float dsum[256];
    const int b = blockIdx.x, t = threadIdx.x;
    const int sBeg = binStart[b];
    const int count = min(binStart[b + 1] - sBeg, BIN_CAP);

    sCnt[t] = 0; sCur[t] = 0; dsum[t] = 0.f;
    __syncthreads();
    for (int i = t; i < count; i += 256) {
        int2 e = staging[sBeg + i];
        sEnt[i] = e;
        int dl = e.x >> 17;
        atomicAdd(&sCnt[dl], 1);
        atomicAdd(&dsum[dl], __int_as_float(e.y));
    }
    __syncthreads();
    const int n0 = b << 8;
    const int Cl = min(256, N - n0);
    if (t < Cl) invD[n0 + t] = 1.f / (dsum[t] + 1e-16f);
    int v = sCnt[t];
    sScan[t] = v;
    __syncthreads();
    for (int off = 1; off < 256; off <<= 1) {
        int u = (t >= off) ? sScan[t - off] : 0;
        __syncthreads();
        sScan[t] += u;
        __syncthreads();
    }
    int ex = sScan[t] - v;
    __syncthreads();
    sScan[t] = ex;                       // exclusive scan in place
    if (t < Cl) offsets[n0 + t] = sBeg + ex;
    __syncthreads();
    for (int i = t; i < count; i += 256) {
        int2 e = sEnt[i];
        int dl = e.x >> 17;
        int pos = sBeg + sScan[dl] + atomicAdd(&sCur[dl], 1);
        staging[pos] = make_int2(e.x & 0x1FFFF, e.y);   // {src, num}
    }
}

// ---------------- aggregate: wave per dst node, 4 edges per uint2 gather ----
// h row = 64 bf16 = 128B = 16 uint2 (256B-aligned array). Preload lanes fold
// invDenom into the edge weight: w = num * invD[src] (parallel 4B L2 gather),
// then shfl-broadcast (src, w). quarter = lane>>4 picks edge j..j+3;
// cg = lane&15 picks a bf16x4 channel group.  (R18 measured-best form.)
__global__ __launch_bounds__(256) void aggregate_kernel(
    const int* __restrict__ offsets, const int2* __restrict__ sortedPair,
    const uint2* __restrict__ hbQ, const float* __restrict__ invD,
    const float* __restrict__ bias, float* __restrict__ out, int N)
{
    int gw = (blockIdx.x * blockDim.x + threadIdx.x) >> 6;
    int lane = threadIdx.x & 63;
    if (gw >= N) return;
    int beg = offsets[gw], end = offsets[gw + 1];
    const int quarter = lane >> 4;
    const int cg = lane & 15;
    float a0 = 0.f, a1 = 0.f, a2 = 0.f, a3 = 0.f;
    for (int e0 = beg; e0 < end; e0 += 64) {
        int idx = e0 + lane;
        int srcL = 0; float wL = 0.f;
        if (idx < end) {
            int2 p = sortedPair[idx];
            srcL = p.x;
            wL = __int_as_float(p.y) * invD[p.x];   // parallel across lanes
        }
        int cnt = min(64, end - e0);
        int j = 0;
        for (; j + 16 <= cnt; j += 16) {
            #pragma unroll
            for (int u = 0; u < 4; ++u) {
                int jj = j + 4 * u + quarter;
                int s = __shfl(srcL, jj);
                float wv = __shfl(wL, jj);
                uint2 g = hbQ[(size_t)s * 16 + cg];
                a0 = fmaf(bf2f((unsigned short)(g.x & 0xFFFFu)), wv, a0);
                a1 = fmaf(bf2f((unsigned short)(g.x >> 16)), wv, a1);
                a2 = fmaf(bf2f((unsigned short)(g.y & 0xFFFFu)), wv, a2);
                a3 = fmaf(bf2f((unsigned short)(g.y >> 16)), wv, a3);
            }
        }
        for (; j < cnt; j += 4) {
            int jj = j + quarter;           // <= 63 always (j<=60, quarter<=3)
            int s = __shfl(srcL, jj);
            float wv = __shfl(wL, jj);
            uint2 g = hbQ[(size_t)s * 16 + cg];
            a0 = fmaf(bf2f((unsigned short)(g.x & 0xFFFFu)), wv, a0);
            a1 = fmaf(bf2f((unsigned short)(g.x >> 16)), wv, a1);
            a2 = fmaf(bf2f((unsigned short)(g.y & 0xFFFFu)), wv, a2);
            a3 = fmaf(bf2f((unsigned short)(g.y >> 16)), wv, a3);
        }
    }
    a0 += __shfl_xor(a0, 16); a0 += __shfl_xor(a0, 32);
    a1 += __shfl_xor(a1, 16); a1 += __shfl_xor(a1, 32);
    a2 += __shfl_xor(a2, 16); a2 += __shfl_xor(a2, 32);
    a3 += __shfl_xor(a3, 16); a3 += __shfl_xor(a3, 32);
    if (lane < 16) {
        float4 bq = reinterpret_cast<const float4*>(bias)[cg];
        float4 o;
        o.x = a0 + bq.x; o.y = a1 + bq.y; o.z = a2 + bq.z; o.w = a3 + bq.w;
        reinterpret_cast<float4*>(out)[(size_t)gw * 16 + cg] = o;
    }
}

extern "C" void kernel_launch(void* const* d_in, const int* in_sizes, int n_in,
                              void* d_out, int out_size, void* d_ws, size_t ws_size,
                              hipStream_t stream) {
    const float* x    = (const float*)d_in[0];
    const int*   ei   = (const int*)d_in[1];
    // d_in[2] = rank_mapping (unused)
    const float* W1   = (const float*)d_in[3];
    const float* Wp   = (const float*)d_in[4];
    const float* bp   = (const float*)d_in[5];
    const float* bias = (const float*)d_in[6];
    float* out = (float*)d_out;

    const int N = in_sizes[0] / 128;
    const int E = in_sizes[1] / 2;
    const int B = (N + 255) >> 8;            // dst bins of 256 nodes (391)
    const int G = (E + EPB - 1) / EPB;       // real pass blocks (306)
    const int G8 = (G + 7) & ~7;             // padded to XCD multiple (312)
    const int NTB = (N + 255) / 256;         // NT blocks, 256 nodes each (391)

    // workspace layout:
    // hbD[N*64 bf16, at base: 256B-aligned] | a[N] | b[N] | invD[N] |
    // C[G8*B] | S[B] | binStart[B+1] | offsets[N+1] | staging[E] int2
    unsigned short* hbD = (unsigned short*)d_ws;       // base is page-aligned
    float* aArr     = (float*)(hbD + (size_t)N * 64);
    float* bArr     = aArr + N;
    float* invD     = bArr + N;
    int*   C        = (int*)(invD + N);
    int*   S        = C + (size_t)G8 * B;
    int*   binStart = S + B;
    int*   offsets  = binStart + (B + 1);
    int*   stRaw    = offsets + (N + 1);
    stRaw = (int*)(((uintptr_t)stRaw + 7) & ~(uintptr_t)7);
    int2*  staging  = (int2*)stRaw;

    // pass1 blocks FIRST so they dispatch early and overlap node transform.
    fused_nt_count_kernel<<<G8 + NTB, 256, 0, stream>>>(
        x, W1, Wp, ei, hbD, aArr, bArr, C, N, E, G8, B);

    colscan_kernel<<<B, 256, 0, stream>>>(C, S, G8, B);

    binscan_kernel<<<1, 256, 0, stream>>>(S, binStart, offsets, B, N, E);

    pass2_kernel<<<G8, 1024, 0, stream>>>(ei, aArr, bArr, bp, C, binStart,
                                          staging, E, B);

    localsort_kernel<<<B, 256, 0, stream>>>(binStart, staging, offsets, invD, N);

    aggregate_kernel<<<(N * 64 + 255) / 256, 256, 0, stream>>>(
        offsets, staging, reinterpret_cast<const uint2*>(hbD), invD, bias, out, N);
}